// Round 1
// baseline (624.591 us; speedup 1.0000x reference)
//
#include <hip/hip_runtime.h>
#include <hip/hip_bf16.h>

// Viterbi CRF decode: B=512, T=512, K=64.
// Round 3: forward = ONE wave per batch (64 thr). Lane j owns next-tag j.
// Score vector is lane-distributed in a single VGPR; prev-scores broadcast
// via v_readlane (imm lane). Transition column trans[i][j] held in 64 VGPRs
// per lane. No LDS / no barriers on the per-step critical path (the 4-wave
// version paid ~1300 cy/step in barrier + LDS round-trip; this is pure VALU).
// Argmax: 8 ascending strict-> chains of 8 (ILP=8), merged low-group-first
// => reproduces jnp.argmax first-index tie-break. FP association
// (score + trans) + emit kept exactly -> bitwise-identical scores.
// Backtrace kernel unchanged (verified).
// Workspace: hist uint8 [B][512][K] = 16.78 MB (row 511 pad) + best_last[B].

#define TT 512
#define BB 512
#define KK 64

#define NEG_INF (-3.402823466e38f)

__global__ __launch_bounds__(64) void viterbi_fwd(
    const float* __restrict__ emissions,   // [B,T,K]
    const int* __restrict__ attn_mask,     // [B,T]
    const float* __restrict__ start_t,     // [K]
    const float* __restrict__ end_t,       // [K]
    const float* __restrict__ trans,       // [K,K]
    unsigned char* __restrict__ hist,      // [B,512,K] (row 511 pad)
    int* __restrict__ best_last)           // [B]
{
    const int b = blockIdx.x;
    const int j = threadIdx.x & 63;

    // this lane's transition column: tc[i] = trans[i][j]
    float tc[KK];
#pragma unroll
    for (int i = 0; i < KK; ++i) tc[i] = trans[i * KK + j];

    const float* eb = emissions + (size_t)b * TT * KK;
    const int*   mb = attn_mask + (size_t)b * TT;
    unsigned char* hb = hist + (size_t)b * TT * KK;

    // score vector lives lane-distributed: lane j holds score[j]
    float score = start_t[j] + eb[j];

    // 2-deep prefetch rings for emissions row and mask
    float e0 = eb[KK + j];
    float e1 = eb[2 * KK + j];
    int   m0 = mb[1];
    int   m1 = mb[2];

    for (int t = 1; t < TT; ++t) {
        float e = e0; e0 = e1;
        int   m = m0; m0 = m1;
        int tn = (t + 2 < TT) ? (t + 2) : (TT - 1);
        e1 = eb[(size_t)tn * KK + j];
        m1 = mb[tn];

        // 8 groups of 8 prev-tags, ascending strict-> chains (first-index
        // tie rule), then ascending merge of group winners.
        float gv[8];
        int   gi[8];
#pragma unroll
        for (int g = 0; g < 8; ++g) {
            const int base = g * 8;
            float s0 = __uint_as_float(
                __builtin_amdgcn_readlane(__float_as_uint(score), base));
            float bv = (s0 + tc[base]) + e;
            int   bi = base;
#pragma unroll
            for (int q = 1; q < 8; ++q) {
                float s = __uint_as_float(
                    __builtin_amdgcn_readlane(__float_as_uint(score), base + q));
                float c = (s + tc[base + q]) + e;
                if (c > bv) { bv = c; bi = base + q; }
            }
            gv[g] = bv;
            gi[g] = bi;
        }
        float best = gv[0];
        int   bi   = gi[0];
#pragma unroll
        for (int g = 1; g < 8; ++g)
            if (gv[g] > best) { best = gv[g]; bi = gi[g]; }

        // history recorded unconditionally (reference scan records idx
        // regardless of mask; mask applied in backtrace)
        hb[(size_t)(t - 1) * KK + j] = (unsigned char)bi;
        // freeze past sequence end
        score = m ? best : score;
    }

    // final: add end transitions, argmax over tags (first-index ties)
    float fin = score + end_t[j];
    __shared__ float sv[KK];
    sv[j] = fin;
    __syncthreads();
    if (j == 0) {
        float bv = sv[0];
        int   bt = 0;
#pragma unroll
        for (int k = 1; k < KK; ++k) {
            float v = sv[k];
            if (v > bv) { bv = v; bt = k; }
        }
        best_last[b] = bt;
    }
}

__global__ __launch_bounds__(64) void viterbi_bt(
    const unsigned char* __restrict__ hist,  // [B,512,K]
    const int* __restrict__ attn_mask,       // [B,T]
    const int* __restrict__ best_last,       // [B]
    int* __restrict__ out)                   // [B,T] int32
{
    const int b = blockIdx.x;
    const int l = threadIdx.x;
    __shared__ int path[TT];

    const unsigned int* hw = (const unsigned int*)(hist + (size_t)b * TT * KK);
    const int* mb = attn_mask + (size_t)b * TT;

    int tag = best_last[b];          // broadcast (uniform on all lanes)
    if (l == 0) path[TT - 1] = tag;

    unsigned int dwA[16], dwB[16];
    int mA, mB;

    auto loadChunk = [&](int c, unsigned int (&dw)[16], int& mreg) {
#pragma unroll
        for (int q4 = 0; q4 < 16; ++q4)
            dw[q4] = hw[c * 1024 + q4 * 64 + l];   // 4 rows per wave-load
        int midx = c * 64 + l + 1;
        if (midx > TT - 1) midx = TT - 1;
        mreg = mb[midx];                            // lane l: mask[b][c*64+l+1]
    };
    auto procChunk = [&](int c, unsigned int (&dw)[16], int mreg) {
#pragma unroll
        for (int q = 63; q >= 0; --q) {
            int r = c * 64 + q;
            if (r < TT - 1) {
                // byte hist[r][tag]: local dword q*16+(tag>>2)
                unsigned int d = __shfl(dw[q >> 2], ((q & 3) << 4) + (tag >> 2));
                int pv = (int)((d >> ((tag & 3) << 3)) & 0xFFu);
                int m  = __shfl(mreg, q);
                tag = m ? pv : tag;
                if (l == 0) path[r] = tag;
            }
        }
    };

    loadChunk(7, dwA, mA);
    for (int c = 7; c >= 1; c -= 2) {
        loadChunk(c - 1, dwB, mB);
        procChunk(c, dwA, mA);
        if (c >= 2) loadChunk(c - 2, dwA, mA);
        procChunk(c - 1, dwB, mB);
    }

    __syncthreads();
#pragma unroll
    for (int cc = 0; cc < 8; ++cc)
        out[(size_t)b * TT + cc * 64 + l] = path[cc * 64 + l];
}

extern "C" void kernel_launch(void* const* d_in, const int* in_sizes, int n_in,
                              void* d_out, int out_size, void* d_ws, size_t ws_size,
                              hipStream_t stream) {
    const float* emissions = (const float*)d_in[0];
    const int* attn_mask   = (const int*)d_in[1];
    const float* start_t   = (const float*)d_in[2];
    const float* end_t     = (const float*)d_in[3];
    const float* trans     = (const float*)d_in[4];
    int* out = (int*)d_out;

    unsigned char* hist = (unsigned char*)d_ws;
    int* best_last = (int*)((char*)d_ws + (size_t)BB * TT * KK);

    viterbi_fwd<<<BB, KK, 0, stream>>>(emissions, attn_mask, start_t, end_t,
                                       trans, hist, best_last);
    viterbi_bt<<<BB, KK, 0, stream>>>(hist, attn_mask, best_last, out);
}

// Round 2
// 624.261 us; speedup vs baseline: 1.0005x; 1.0005x over previous
//
#include <hip/hip_runtime.h>
#include <hip/hip_bf16.h>

// Viterbi CRF decode: B=512, T=512, K=64.
// Round 4: same one-wave-per-batch structure as round 3, but with
// __launch_bounds__(64, 1). Round 3 regressed because the default
// occupancy heuristic capped the kernel at 48 VGPRs -> tc[64] spilled to
// scratch -> 64 scratch reloads per step with a single wave and no TLP to
// hide them (VGPR_Count=48, VALUBusy 29% in rocprof). waves-per-eu=1
// lifts the cap (~512 VGPR budget) so the transition column stays
// register-resident and the per-step critical path is pure VALU:
// 64 readlane + 128 add + ~190 cmp/cndmask.
// Argmax: 8 ascending strict-> chains of 8 (ILP=8), merged low-group-first
// => reproduces jnp.argmax first-index tie-break. FP association
// (score + trans) + emit kept exactly -> bitwise-identical scores.
// Backtrace kernel unchanged (verified).
// Workspace: hist uint8 [B][512][K] = 16.78 MB (row 511 pad) + best_last[B].

#define TT 512
#define BB 512
#define KK 64

#define NEG_INF (-3.402823466e38f)

__global__ __launch_bounds__(64, 1) void viterbi_fwd(
    const float* __restrict__ emissions,   // [B,T,K]
    const int* __restrict__ attn_mask,     // [B,T]
    const float* __restrict__ start_t,     // [K]
    const float* __restrict__ end_t,       // [K]
    const float* __restrict__ trans,       // [K,K]
    unsigned char* __restrict__ hist,      // [B,512,K] (row 511 pad)
    int* __restrict__ best_last)           // [B]
{
    const int b = blockIdx.x;
    const int j = threadIdx.x & 63;

    // this lane's transition column: tc[i] = trans[i][j]  (register-resident)
    float tc[KK];
#pragma unroll
    for (int i = 0; i < KK; ++i) tc[i] = trans[i * KK + j];

    const float* eb = emissions + (size_t)b * TT * KK;
    const int*   mb = attn_mask + (size_t)b * TT;
    unsigned char* hb = hist + (size_t)b * TT * KK;

    // score vector lives lane-distributed: lane j holds score[j]
    float score = start_t[j] + eb[j];

    // 2-deep prefetch rings for emissions row and mask
    float e0 = eb[KK + j];
    float e1 = eb[2 * KK + j];
    int   m0 = mb[1];
    int   m1 = mb[2];

    for (int t = 1; t < TT; ++t) {
        float e = e0; e0 = e1;
        int   m = m0; m0 = m1;
        int tn = (t + 2 < TT) ? (t + 2) : (TT - 1);
        e1 = eb[(size_t)tn * KK + j];
        m1 = mb[tn];

        // 8 groups of 8 prev-tags, ascending strict-> chains (first-index
        // tie rule), then ascending merge of group winners.
        float gv[8];
        int   gi[8];
#pragma unroll
        for (int g = 0; g < 8; ++g) {
            const int base = g * 8;
            float s0 = __uint_as_float(
                __builtin_amdgcn_readlane(__float_as_uint(score), base));
            float bv = (s0 + tc[base]) + e;
            int   bi = base;
#pragma unroll
            for (int q = 1; q < 8; ++q) {
                float s = __uint_as_float(
                    __builtin_amdgcn_readlane(__float_as_uint(score), base + q));
                float c = (s + tc[base + q]) + e;
                if (c > bv) { bv = c; bi = base + q; }
            }
            gv[g] = bv;
            gi[g] = bi;
        }
        float best = gv[0];
        int   bi   = gi[0];
#pragma unroll
        for (int g = 1; g < 8; ++g)
            if (gv[g] > best) { best = gv[g]; bi = gi[g]; }

        // history recorded unconditionally (reference scan records idx
        // regardless of mask; mask applied in backtrace)
        hb[(size_t)(t - 1) * KK + j] = (unsigned char)bi;
        // freeze past sequence end
        score = m ? best : score;
    }

    // final: add end transitions, argmax over tags (first-index ties)
    float fin = score + end_t[j];
    __shared__ float sv[KK];
    sv[j] = fin;
    __syncthreads();
    if (j == 0) {
        float bv = sv[0];
        int   bt = 0;
#pragma unroll
        for (int k = 1; k < KK; ++k) {
            float v = sv[k];
            if (v > bv) { bv = v; bt = k; }
        }
        best_last[b] = bt;
    }
}

__global__ __launch_bounds__(64) void viterbi_bt(
    const unsigned char* __restrict__ hist,  // [B,512,K]
    const int* __restrict__ attn_mask,       // [B,T]
    const int* __restrict__ best_last,       // [B]
    int* __restrict__ out)                   // [B,T] int32
{
    const int b = blockIdx.x;
    const int l = threadIdx.x;
    __shared__ int path[TT];

    const unsigned int* hw = (const unsigned int*)(hist + (size_t)b * TT * KK);
    const int* mb = attn_mask + (size_t)b * TT;

    int tag = best_last[b];          // broadcast (uniform on all lanes)
    if (l == 0) path[TT - 1] = tag;

    unsigned int dwA[16], dwB[16];
    int mA, mB;

    auto loadChunk = [&](int c, unsigned int (&dw)[16], int& mreg) {
#pragma unroll
        for (int q4 = 0; q4 < 16; ++q4)
            dw[q4] = hw[c * 1024 + q4 * 64 + l];   // 4 rows per wave-load
        int midx = c * 64 + l + 1;
        if (midx > TT - 1) midx = TT - 1;
        mreg = mb[midx];                            // lane l: mask[b][c*64+l+1]
    };
    auto procChunk = [&](int c, unsigned int (&dw)[16], int mreg) {
#pragma unroll
        for (int q = 63; q >= 0; --q) {
            int r = c * 64 + q;
            if (r < TT - 1) {
                // byte hist[r][tag]: local dword q*16+(tag>>2)
                unsigned int d = __shfl(dw[q >> 2], ((q & 3) << 4) + (tag >> 2));
                int pv = (int)((d >> ((tag & 3) << 3)) & 0xFFu);
                int m  = __shfl(mreg, q);
                tag = m ? pv : tag;
                if (l == 0) path[r] = tag;
            }
        }
    };

    loadChunk(7, dwA, mA);
    for (int c = 7; c >= 1; c -= 2) {
        loadChunk(c - 1, dwB, mB);
        procChunk(c, dwA, mA);
        if (c >= 2) loadChunk(c - 2, dwA, mA);
        procChunk(c - 1, dwB, mB);
    }

    __syncthreads();
#pragma unroll
    for (int cc = 0; cc < 8; ++cc)
        out[(size_t)b * TT + cc * 64 + l] = path[cc * 64 + l];
}

extern "C" void kernel_launch(void* const* d_in, const int* in_sizes, int n_in,
                              void* d_out, int out_size, void* d_ws, size_t ws_size,
                              hipStream_t stream) {
    const float* emissions = (const float*)d_in[0];
    const int* attn_mask   = (const int*)d_in[1];
    const float* start_t   = (const float*)d_in[2];
    const float* end_t     = (const float*)d_in[3];
    const float* trans     = (const float*)d_in[4];
    int* out = (int*)d_out;

    unsigned char* hist = (unsigned char*)d_ws;
    int* best_last = (int*)((char*)d_ws + (size_t)BB * TT * KK);

    viterbi_fwd<<<BB, KK, 0, stream>>>(emissions, attn_mask, start_t, end_t,
                                       trans, hist, best_last);
    viterbi_bt<<<BB, KK, 0, stream>>>(hist, attn_mask, best_last, out);
}

// Round 3
// 507.847 us; speedup vs baseline: 1.2299x; 1.2292x over previous
//
#include <hip/hip_runtime.h>
#include <hip/hip_bf16.h>

// Viterbi CRF decode: B=512, T=512, K=64.
// Round 5: one wave per batch (64 thr), transitions in LDS.
// Round 3/4 post-mortem: VGPR_Count=48 with identical codegen across
// launch-bounds variants proves the compiler REFUSES to keep tc[64] in
// VGPRs (MachineLICM pressure heuristic) and re-loads trans from global
// every step -> ~1760 cy/step of exposed L2 latency with 1 wave/SIMD and
// no TLP (VALUBusy 29%). Fix: stage trans[64][64] into LDS once; lane j
// reads candidate i at ds_read_b32 base(&lds_t[j]) offset:i*256 -- static
// addresses, zero addr VALU, 2-way bank alias (free, m136), LDS pipe
// overlaps VALU. Live register state ~40 VGPRs, nothing to spill.
// Score broadcast via v_readlane (imm lane). Argmax: 8 ascending strict->
// chains of 8 (ILP=8), merged low-group-first => jnp.argmax first-index
// tie-break. FP association (score + trans) + emit kept exactly ->
// bitwise-identical scores. Backtrace kernel unchanged (verified).
// Workspace: hist uint8 [B][512][K] = 16.78 MB (row 511 pad) + best_last[B].

#define TT 512
#define BB 512
#define KK 64

#define NEG_INF (-3.402823466e38f)

__global__ __launch_bounds__(64) void viterbi_fwd(
    const float* __restrict__ emissions,   // [B,T,K]
    const int* __restrict__ attn_mask,     // [B,T]
    const float* __restrict__ start_t,     // [K]
    const float* __restrict__ end_t,       // [K]
    const float* __restrict__ trans,       // [K,K]
    unsigned char* __restrict__ hist,      // [B,512,K] (row 511 pad)
    int* __restrict__ best_last)           // [B]
{
    const int b = blockIdx.x;
    const int j = threadIdx.x & 63;

    // stage transitions into LDS: lds_t[i*64+j] = trans[i][j]
    __shared__ float lds_t[KK * KK];
#pragma unroll
    for (int i = 0; i < KK; ++i) lds_t[i * KK + j] = trans[i * KK + j];
    __syncthreads();

    // lane j's column base: candidate i at tcb[i*64] (ds offset i*256)
    const float* tcb = &lds_t[j];

    const float* eb = emissions + (size_t)b * TT * KK;
    const int*   mb = attn_mask + (size_t)b * TT;
    unsigned char* hb = hist + (size_t)b * TT * KK;

    // score vector lives lane-distributed: lane j holds score[j]
    float score = start_t[j] + eb[j];

    // 2-deep prefetch rings for emissions row and mask
    float e0 = eb[KK + j];
    float e1 = eb[2 * KK + j];
    int   m0 = mb[1];
    int   m1 = mb[2];

    for (int t = 1; t < TT; ++t) {
        float e = e0; e0 = e1;
        int   m = m0; m0 = m1;
        int tn = (t + 2 < TT) ? (t + 2) : (TT - 1);
        e1 = eb[(size_t)tn * KK + j];
        m1 = mb[tn];

        // 8 groups of 8 prev-tags, ascending strict-> chains (first-index
        // tie rule), then ascending merge of group winners.
        float gv[8];
        int   gi[8];
#pragma unroll
        for (int g = 0; g < 8; ++g) {
            const int base = g * 8;
            float s0 = __uint_as_float(
                __builtin_amdgcn_readlane(__float_as_uint(score), base));
            float bv = (s0 + tcb[base * KK]) + e;
            int   bi = base;
#pragma unroll
            for (int q = 1; q < 8; ++q) {
                float s = __uint_as_float(
                    __builtin_amdgcn_readlane(__float_as_uint(score), base + q));
                float c = (s + tcb[(base + q) * KK]) + e;
                if (c > bv) { bv = c; bi = base + q; }
            }
            gv[g] = bv;
            gi[g] = bi;
        }
        float best = gv[0];
        int   bi   = gi[0];
#pragma unroll
        for (int g = 1; g < 8; ++g)
            if (gv[g] > best) { best = gv[g]; bi = gi[g]; }

        // history recorded unconditionally (reference scan records idx
        // regardless of mask; mask applied in backtrace)
        hb[(size_t)(t - 1) * KK + j] = (unsigned char)bi;
        // freeze past sequence end
        score = m ? best : score;
    }

    // final: add end transitions, argmax over tags (first-index ties)
    float fin = score + end_t[j];
    __shared__ float sv[KK];
    sv[j] = fin;
    __syncthreads();
    if (j == 0) {
        float bv = sv[0];
        int   bt = 0;
#pragma unroll
        for (int k = 1; k < KK; ++k) {
            float v = sv[k];
            if (v > bv) { bv = v; bt = k; }
        }
        best_last[b] = bt;
    }
}

__global__ __launch_bounds__(64) void viterbi_bt(
    const unsigned char* __restrict__ hist,  // [B,512,K]
    const int* __restrict__ attn_mask,       // [B,T]
    const int* __restrict__ best_last,       // [B]
    int* __restrict__ out)                   // [B,T] int32
{
    const int b = blockIdx.x;
    const int l = threadIdx.x;
    __shared__ int path[TT];

    const unsigned int* hw = (const unsigned int*)(hist + (size_t)b * TT * KK);
    const int* mb = attn_mask + (size_t)b * TT;

    int tag = best_last[b];          // broadcast (uniform on all lanes)
    if (l == 0) path[TT - 1] = tag;

    unsigned int dwA[16], dwB[16];
    int mA, mB;

    auto loadChunk = [&](int c, unsigned int (&dw)[16], int& mreg) {
#pragma unroll
        for (int q4 = 0; q4 < 16; ++q4)
            dw[q4] = hw[c * 1024 + q4 * 64 + l];   // 4 rows per wave-load
        int midx = c * 64 + l + 1;
        if (midx > TT - 1) midx = TT - 1;
        mreg = mb[midx];                            // lane l: mask[b][c*64+l+1]
    };
    auto procChunk = [&](int c, unsigned int (&dw)[16], int mreg) {
#pragma unroll
        for (int q = 63; q >= 0; --q) {
            int r = c * 64 + q;
            if (r < TT - 1) {
                // byte hist[r][tag]: local dword q*16+(tag>>2)
                unsigned int d = __shfl(dw[q >> 2], ((q & 3) << 4) + (tag >> 2));
                int pv = (int)((d >> ((tag & 3) << 3)) & 0xFFu);
                int m  = __shfl(mreg, q);
                tag = m ? pv : tag;
                if (l == 0) path[r] = tag;
            }
        }
    };

    loadChunk(7, dwA, mA);
    for (int c = 7; c >= 1; c -= 2) {
        loadChunk(c - 1, dwB, mB);
        procChunk(c, dwA, mA);
        if (c >= 2) loadChunk(c - 2, dwA, mA);
        procChunk(c - 1, dwB, mB);
    }

    __syncthreads();
#pragma unroll
    for (int cc = 0; cc < 8; ++cc)
        out[(size_t)b * TT + cc * 64 + l] = path[cc * 64 + l];
}

extern "C" void kernel_launch(void* const* d_in, const int* in_sizes, int n_in,
                              void* d_out, int out_size, void* d_ws, size_t ws_size,
                              hipStream_t stream) {
    const float* emissions = (const float*)d_in[0];
    const int* attn_mask   = (const int*)d_in[1];
    const float* start_t   = (const float*)d_in[2];
    const float* end_t     = (const float*)d_in[3];
    const float* trans     = (const float*)d_in[4];
    int* out = (int*)d_out;

    unsigned char* hist = (unsigned char*)d_ws;
    int* best_last = (int*)((char*)d_ws + (size_t)BB * TT * KK);

    viterbi_fwd<<<BB, KK, 0, stream>>>(emissions, attn_mask, start_t, end_t,
                                       trans, hist, best_last);
    viterbi_bt<<<BB, KK, 0, stream>>>(hist, attn_mask, best_last, out);
}